// Round 8
// baseline (187.509 us; speedup 1.0000x reference)
//
#include <hip/hip_runtime.h>

#define DIM 512
#define HIDDEN 1024
#define H2 2048        // 2*HIDDEN
#define NEXP 32
#define TOPK 4
#define TOKENS 64
#define NPAIR (TOKENS*TOPK)   // 256
#define PADK 8                // ushort pad per LDS row (2-way bank alias = free)

typedef __attribute__((ext_vector_type(8))) short short8;
typedef __attribute__((ext_vector_type(4))) float fp32x4;
typedef __attribute__((ext_vector_type(4))) unsigned short ushort4v;

// f32 -> bf16 round-nearest-even
__device__ __forceinline__ unsigned short f2bf_rne(float f) {
    unsigned u = __float_as_uint(f);
    return (unsigned short)((u + 0x7FFFu + ((u >> 16) & 1u)) >> 16);
}
// f32 -> packed (hi | lo<<16): hi = truncate-to-bf16, lo = RNE(residual)
__device__ __forceinline__ unsigned split2p(float f) {
    unsigned u = __float_as_uint(f);
    unsigned short h = (unsigned short)(u >> 16);
    float hf = __uint_as_float(u & 0xFFFF0000u);
    unsigned short lo = f2bf_rne(f - hf);
    return (unsigned)h | ((unsigned)lo << 16);
}
__device__ __forceinline__ float dot4f(float4 a, float4 b) {
    return a.x*b.x + a.y*b.y + a.z*b.z + a.w*b.w;
}

// ---------------- fused router: logits + top4 + softmax + expert lists ----
// ONE block, 256 threads. x tiled via LDS; logits in padded LDS; lists from LDS.
__global__ __launch_bounds__(256) void router_fused(
        const float* __restrict__ x, const float* __restrict__ Wg,
        const float* __restrict__ bg, int* __restrict__ idxw,
        float* __restrict__ eww, int* __restrict__ counts,
        int* __restrict__ lists) {
    __shared__ float xs[16][DIM];          // 32 KB
    __shared__ float g[TOKENS][NEXP + 1];  // 8.25 KB (pad kills bank conflict)
    __shared__ int   sidx[NPAIR];          // 1 KB
    int tid = threadIdx.x;
    for (int tg = 0; tg < TOKENS; tg += 16) {
        __syncthreads();
        for (int i = tid; i < 16*(DIM/4); i += 256) {
            int j = i >> 7, dd = i & 127;
            *(float4*)&xs[j][4*dd] = *(const float4*)(x + (size_t)(tg + j)*DIM + 4*dd);
        }
        __syncthreads();
        for (int q = tid; q < 16*NEXP; q += 256) {   // 2 dots/thread
            int j = q >> 5, e = q & 31;
            const float* wr = Wg + e*DIM;
            float acc = 0.f;
            for (int d = 0; d < DIM; d += 4) {
                float4 xv = *(const float4*)&xs[j][d];
                float4 wv = *(const float4*)(wr + d);
                acc += dot4f(xv, wv);
            }
            g[tg + j][e] = acc + bg[e];
        }
    }
    __syncthreads();
    if (tid < TOKENS) {
        int sel[TOPK]; float val[TOPK];
        bool used[NEXP];
        for (int i = 0; i < NEXP; ++i) used[i] = false;
        for (int k = 0; k < TOPK; ++k) {
            float best = -1e30f; int bi = 0;
            for (int ee = 0; ee < NEXP; ++ee) {
                float gv = g[tid][ee];
                if (!used[ee] && gv > best) { best = gv; bi = ee; }
            }
            used[bi] = true; sel[k] = bi; val[k] = best;
        }
        float m = val[0];
        float p[TOPK]; float s = 0.f;
        for (int k = 0; k < TOPK; ++k) { p[k] = __expf(val[k] - m); s += p[k]; }
        float inv = 1.f / s;
        for (int k = 0; k < TOPK; ++k) {
            idxw[tid*TOPK + k] = sel[k];
            sidx[tid*TOPK + k] = sel[k];
            eww[tid*TOPK + k]  = p[k] * inv;
        }
    }
    __syncthreads();
    if (tid < NEXP) {
        int cnt = 0;
        for (int p = 0; p < NPAIR; ++p) {
            if (sidx[p] == tid) lists[tid*TOKENS + cnt++] = p;
        }
        counts[tid] = cnt;
    }
}

// ---------------- expert up-proj + swiglu (MFMA, w split hi/lo, x bf16) ---
// block = 256 thr = 4 waves; wave owns 16 raw w1 rows x 16 tokens.
// grid (NEXP, H2/64 = 32). 2 MFMAs per K-tile: wh*xh + wl*xh. Depth-2 prefetch.
__global__ __launch_bounds__(256, 4) void expert_up(
        const float* __restrict__ x, const float* __restrict__ w1,
        const float* __restrict__ b1, const int* __restrict__ counts,
        const int* __restrict__ lists, float* __restrict__ act) {
    int e = blockIdx.x;
    int n = counts[e];
    if (n == 0) return;
    int tid = threadIdx.x;
    int wv = tid >> 6, l = tid & 63;
    int lr = l & 15, lg = l >> 4;          // A row-in-tile / k-group
    __shared__ unsigned short xh[16][DIM + PADK];   // 16.25 KB
    int r0 = blockIdx.y * 64 + wv * 16;    // raw row tile base (0..2047)
    const float4* w4 = (const float4*)(w1 + ((size_t)e*H2 + r0 + lr) * DIM + lg * 8);

    for (int t0 = 0; t0 < n; t0 += 16) {
        int nn = min(16, n - t0);
        __syncthreads();
        for (int i = tid; i < 16 * (DIM/4); i += 256) {
            int j = i >> 7, dd = i & 127;             // DIM/4 = 128
            float4 v = make_float4(0.f, 0.f, 0.f, 0.f);
            if (j < nn) {
                int p = lists[e*TOKENS + t0 + j];
                v = *(const float4*)(x + (size_t)(p >> 2)*DIM + 4*dd);
            }
            ushort4v hv;
            hv[0] = f2bf_rne(v.x); hv[1] = f2bf_rne(v.y);
            hv[2] = f2bf_rne(v.z); hv[3] = f2bf_rne(v.w);
            *(ushort4v*)&xh[j][4*dd] = hv;
        }
        __syncthreads();

        fp32x4 acc = {0.f, 0.f, 0.f, 0.f};
        float4 c0 = w4[0], c1 = w4[1];      // kt=0 in flight
        for (int kt = 0; kt < 16; ++kt) {
            float4 n0, n1;
            if (kt < 15) { n0 = w4[8*(kt+1)]; n1 = w4[8*(kt+1) + 1]; }
            short8 ah, al;
            unsigned pk;
            pk = split2p(c0.x); ah[0]=(short)(pk & 0xFFFF); al[0]=(short)(pk >> 16);
            pk = split2p(c0.y); ah[1]=(short)(pk & 0xFFFF); al[1]=(short)(pk >> 16);
            pk = split2p(c0.z); ah[2]=(short)(pk & 0xFFFF); al[2]=(short)(pk >> 16);
            pk = split2p(c0.w); ah[3]=(short)(pk & 0xFFFF); al[3]=(short)(pk >> 16);
            pk = split2p(c1.x); ah[4]=(short)(pk & 0xFFFF); al[4]=(short)(pk >> 16);
            pk = split2p(c1.y); ah[5]=(short)(pk & 0xFFFF); al[5]=(short)(pk >> 16);
            pk = split2p(c1.z); ah[6]=(short)(pk & 0xFFFF); al[6]=(short)(pk >> 16);
            pk = split2p(c1.w); ah[7]=(short)(pk & 0xFFFF); al[7]=(short)(pk >> 16);
            short8 bh = *(const short8*)&xh[lr][kt*32 + lg*8];
            acc = __builtin_amdgcn_mfma_f32_16x16x32_bf16(ah, bh, acc, 0, 0, 0);
            acc = __builtin_amdgcn_mfma_f32_16x16x32_bf16(al, bh, acc, 0, 0, 0);
            c0 = n0; c1 = n1;
        }

        // D: col = l&15 = token, row = (l>>4)*4 + reg.
        int tok = lr;
        if (tok < nn) {
            int p = lists[e*TOKENS + t0 + tok];
            #pragma unroll
            for (int u = 0; u < 2; ++u) {
                int rr = r0 + lg*4 + 2*u;             // even raw row
                float h0 = acc[2*u]   + b1[e*H2 + rr];
                float h1 = acc[2*u+1] + b1[e*H2 + rr + 1];
                float gv = fminf(h0, 7.f);
                float lvv = fminf(fmaxf(h1, -7.f), 7.f);
                float sg = 1.f / (1.f + __expf(-1.702f * gv));
                act[(size_t)p*HIDDEN + (rr >> 1)] = gv * sg * (lvv + 1.f);
            }
        }
    }
}

// ---------------- expert down-proj (MFMA, w2 split hi/lo, act bf16) -------
// block = 256 thr = 4 waves; wave owns 16 w2 rows x 16 tokens.
// grid (NEXP, DIM/64 = 8). Depth-2 prefetch.
__global__ __launch_bounds__(256, 4) void expert_down(
        const float* __restrict__ act, const float* __restrict__ w2,
        const float* __restrict__ b2, const int* __restrict__ counts,
        const int* __restrict__ lists, float* __restrict__ h2) {
    int e = blockIdx.x;
    int n = counts[e];
    if (n == 0) return;
    int tid = threadIdx.x;
    int wv = tid >> 6, l = tid & 63;
    int lr = l & 15, lg = l >> 4;
    __shared__ unsigned short as_[16][HIDDEN + PADK];  // 32.25 KB
    int r0 = blockIdx.y * 64 + wv * 16;    // output row tile base (0..511)
    const float4* w4 = (const float4*)(w2 + ((size_t)e*DIM + r0 + lr) * HIDDEN + lg * 8);

    for (int t0 = 0; t0 < n; t0 += 16) {
        int nn = min(16, n - t0);
        __syncthreads();
        for (int i = tid; i < 16 * (HIDDEN/4); i += 256) {
            int j = i >> 8, dd = i & 255;             // HIDDEN/4 = 256
            float4 v = make_float4(0.f, 0.f, 0.f, 0.f);
            if (j < nn) {
                int p = lists[e*TOKENS + t0 + j];
                v = *(const float4*)(act + (size_t)p*HIDDEN + 4*dd);
            }
            ushort4v hv;
            hv[0] = f2bf_rne(v.x); hv[1] = f2bf_rne(v.y);
            hv[2] = f2bf_rne(v.z); hv[3] = f2bf_rne(v.w);
            *(ushort4v*)&as_[j][4*dd] = hv;
        }
        __syncthreads();

        fp32x4 acc = {0.f, 0.f, 0.f, 0.f};
        float4 c0 = w4[0], c1 = w4[1];
        for (int kt = 0; kt < 32; ++kt) {
            float4 n0, n1;
            if (kt < 31) { n0 = w4[8*(kt+1)]; n1 = w4[8*(kt+1) + 1]; }
            short8 ah, al;
            unsigned pk;
            pk = split2p(c0.x); ah[0]=(short)(pk & 0xFFFF); al[0]=(short)(pk >> 16);
            pk = split2p(c0.y); ah[1]=(short)(pk & 0xFFFF); al[1]=(short)(pk >> 16);
            pk = split2p(c0.z); ah[2]=(short)(pk & 0xFFFF); al[2]=(short)(pk >> 16);
            pk = split2p(c0.w); ah[3]=(short)(pk & 0xFFFF); al[3]=(short)(pk >> 16);
            pk = split2p(c1.x); ah[4]=(short)(pk & 0xFFFF); al[4]=(short)(pk >> 16);
            pk = split2p(c1.y); ah[5]=(short)(pk & 0xFFFF); al[5]=(short)(pk >> 16);
            pk = split2p(c1.z); ah[6]=(short)(pk & 0xFFFF); al[6]=(short)(pk >> 16);
            pk = split2p(c1.w); ah[7]=(short)(pk & 0xFFFF); al[7]=(short)(pk >> 16);
            short8 bh = *(const short8*)&as_[lr][kt*32 + lg*8];
            acc = __builtin_amdgcn_mfma_f32_16x16x32_bf16(ah, bh, acc, 0, 0, 0);
            acc = __builtin_amdgcn_mfma_f32_16x16x32_bf16(al, bh, acc, 0, 0, 0);
            c0 = n0; c1 = n1;
        }

        int tok = lr;
        if (tok < nn) {
            int p = lists[e*TOKENS + t0 + tok];
            #pragma unroll
            for (int u = 0; u < 4; ++u) {
                int rr = r0 + lg*4 + u;
                h2[(size_t)p*DIM + rr] = acc[u] + b2[e*DIM + rr];
            }
        }
    }
}

// ---------------- weighted combine ----------------
__global__ void combine_kernel(const float* __restrict__ h2, const float* __restrict__ eww,
                               float* __restrict__ out) {
    int i = blockIdx.x * 256 + threadIdx.x;   // 0..32767
    int b = i / DIM;
    int c = i % DIM;
    float s = 0.f;
    #pragma unroll
    for (int k = 0; k < TOPK; ++k) {
        s += eww[b*TOPK + k] * h2[(size_t)(b*TOPK + k)*DIM + c];
    }
    out[i] = s;
}

extern "C" void kernel_launch(void* const* d_in, const int* in_sizes, int n_in,
                              void* d_out, int out_size, void* d_ws, size_t ws_size,
                              hipStream_t stream) {
    const float* x  = (const float*)d_in[0];
    const float* Wg = (const float*)d_in[1];
    const float* bg = (const float*)d_in[2];
    const float* w1 = (const float*)d_in[3];
    const float* b1 = (const float*)d_in[4];
    const float* w2 = (const float*)d_in[5];
    const float* b2 = (const float*)d_in[6];
    float* out = (float*)d_out;

    char* ws = (char*)d_ws;
    int*   idxw   = (int*)(ws);                 // 256 ints
    float* eww    = (float*)(ws + 1024);        // 256 floats
    int*   counts = (int*)(ws + 2048);          // 32 ints
    int*   lists  = (int*)(ws + 4096);          // 32*64 ints
    float* act    = (float*)(ws + 16384);                          // 256*1024 f32 = 1 MB
    float* h2     = (float*)(ws + 16384 + (size_t)NPAIR*HIDDEN*4); // 256*512 f32 = 512 KB

    router_fused<<<1, 256, 0, stream>>>(x, Wg, bg, idxw, eww, counts, lists);
    expert_up<<<dim3(NEXP, H2/64), 256, 0, stream>>>(x, w1, b1, counts, lists, act);
    expert_down<<<dim3(NEXP, DIM/64), 256, 0, stream>>>(act, w2, b2, counts, lists, h2);
    combine_kernel<<<TOKENS*DIM/256, 256, 0, stream>>>(h2, eww, out);
}

// Round 9
// 83.036 us; speedup vs baseline: 2.2582x; 2.2582x over previous
//
#include <hip/hip_runtime.h>

#define DIM 512
#define HIDDEN 1024
#define H2 2048        // 2*HIDDEN
#define NEXP 32
#define TOPK 4
#define TOKENS 64
#define NPAIR (TOKENS*TOPK)   // 256
#define PADK 8                // ushort pad per LDS row (2-way bank alias = free)

typedef __attribute__((ext_vector_type(8))) short short8;
typedef __attribute__((ext_vector_type(4))) float fp32x4;
typedef __attribute__((ext_vector_type(4))) unsigned short ushort4v;

// f32 -> bf16 round-nearest-even
__device__ __forceinline__ unsigned short f2bf_rne(float f) {
    unsigned u = __float_as_uint(f);
    return (unsigned short)((u + 0x7FFFu + ((u >> 16) & 1u)) >> 16);
}
// f32 -> packed (hi | lo<<16): hi = truncate-to-bf16, lo = RNE(residual)
__device__ __forceinline__ unsigned split2p(float f) {
    unsigned u = __float_as_uint(f);
    unsigned short h = (unsigned short)(u >> 16);
    float hf = __uint_as_float(u & 0xFFFF0000u);
    unsigned short lo = f2bf_rne(f - hf);
    return (unsigned)h | ((unsigned)lo << 16);
}

// ---------------- router: logits + top4 + softmax (64 blocks) ----------------
__global__ void router_kernel(const float* __restrict__ x, const float* __restrict__ Wg,
                              const float* __restrict__ bg, int* __restrict__ idxw,
                              float* __restrict__ eww) {
    int b = blockIdx.x;
    int e = threadIdx.x;
    __shared__ float g[NEXP];
    if (e < NEXP) {
        const float* xr = x + b * DIM;
        const float* wr = Wg + e * DIM;
        float acc = 0.f;
        for (int d = 0; d < DIM; d += 4) {
            float4 xv = *(const float4*)(xr + d);
            float4 wv = *(const float4*)(wr + d);
            acc += xv.x*wv.x + xv.y*wv.y + xv.z*wv.z + xv.w*wv.w;
        }
        g[e] = acc + bg[e];
    }
    __syncthreads();
    if (threadIdx.x == 0) {
        int sel[TOPK]; float val[TOPK];
        bool used[NEXP];
        for (int i = 0; i < NEXP; ++i) used[i] = false;
        for (int k = 0; k < TOPK; ++k) {
            float best = -1e30f; int bi = 0;
            for (int ee = 0; ee < NEXP; ++ee) {
                if (!used[ee] && g[ee] > best) { best = g[ee]; bi = ee; }
            }
            used[bi] = true; sel[k] = bi; val[k] = best;
        }
        float m = val[0];
        float p[TOPK]; float s = 0.f;
        for (int k = 0; k < TOPK; ++k) { p[k] = __expf(val[k] - m); s += p[k]; }
        float inv = 1.f / s;
        for (int k = 0; k < TOPK; ++k) {
            idxw[b*TOPK + k] = sel[k];
            eww[b*TOPK + k]  = p[k] * inv;
        }
    }
}

// ---------------- per-expert list build (LDS-staged scan) ----------------
__global__ __launch_bounds__(256) void build_lists(
        const int* __restrict__ idxw, int* __restrict__ counts,
        int* __restrict__ lists) {
    __shared__ int sidx[NPAIR];
    int tid = threadIdx.x;
    if (tid < NPAIR) sidx[tid] = idxw[tid];
    __syncthreads();
    if (tid < NEXP) {
        int cnt = 0;
        for (int p = 0; p < NPAIR; ++p) {
            if (sidx[p] == tid) lists[tid*TOKENS + cnt++] = p;
        }
        counts[tid] = cnt;
    }
}

// ---------------- expert up-proj + swiglu (MFMA, w split hi/lo, x bf16) ---
// block = 256 thr = 4 waves; wave owns 16 raw w1 rows x 16 tokens.
// grid (NEXP, H2/64 = 32). 2 MFMAs per K-tile: wh*xh + wl*xh. Depth-2 prefetch.
__global__ __launch_bounds__(256, 4) void expert_up(
        const float* __restrict__ x, const float* __restrict__ w1,
        const float* __restrict__ b1, const int* __restrict__ counts,
        const int* __restrict__ lists, float* __restrict__ act) {
    int e = blockIdx.x;
    int n = counts[e];
    if (n == 0) return;
    int tid = threadIdx.x;
    int wv = tid >> 6, l = tid & 63;
    int lr = l & 15, lg = l >> 4;          // A row-in-tile / k-group
    __shared__ unsigned short xh[16][DIM + PADK];   // 16.25 KB
    int r0 = blockIdx.y * 64 + wv * 16;    // raw row tile base (0..2047)
    const float4* w4 = (const float4*)(w1 + ((size_t)e*H2 + r0 + lr) * DIM + lg * 8);

    for (int t0 = 0; t0 < n; t0 += 16) {
        int nn = min(16, n - t0);
        __syncthreads();
        for (int i = tid; i < 16 * (DIM/4); i += 256) {
            int j = i >> 7, dd = i & 127;             // DIM/4 = 128
            float4 v = make_float4(0.f, 0.f, 0.f, 0.f);
            if (j < nn) {
                int p = lists[e*TOKENS + t0 + j];
                v = *(const float4*)(x + (size_t)(p >> 2)*DIM + 4*dd);
            }
            ushort4v hv;
            hv[0] = f2bf_rne(v.x); hv[1] = f2bf_rne(v.y);
            hv[2] = f2bf_rne(v.z); hv[3] = f2bf_rne(v.w);
            *(ushort4v*)&xh[j][4*dd] = hv;
        }
        __syncthreads();

        fp32x4 acc = {0.f, 0.f, 0.f, 0.f};
        float4 c0 = w4[0], c1 = w4[1];      // kt=0 in flight
        for (int kt = 0; kt < 16; ++kt) {
            float4 n0, n1;
            if (kt < 15) { n0 = w4[8*(kt+1)]; n1 = w4[8*(kt+1) + 1]; }
            short8 ah, al;
            unsigned pk;
            pk = split2p(c0.x); ah[0]=(short)(pk & 0xFFFF); al[0]=(short)(pk >> 16);
            pk = split2p(c0.y); ah[1]=(short)(pk & 0xFFFF); al[1]=(short)(pk >> 16);
            pk = split2p(c0.z); ah[2]=(short)(pk & 0xFFFF); al[2]=(short)(pk >> 16);
            pk = split2p(c0.w); ah[3]=(short)(pk & 0xFFFF); al[3]=(short)(pk >> 16);
            pk = split2p(c1.x); ah[4]=(short)(pk & 0xFFFF); al[4]=(short)(pk >> 16);
            pk = split2p(c1.y); ah[5]=(short)(pk & 0xFFFF); al[5]=(short)(pk >> 16);
            pk = split2p(c1.z); ah[6]=(short)(pk & 0xFFFF); al[6]=(short)(pk >> 16);
            pk = split2p(c1.w); ah[7]=(short)(pk & 0xFFFF); al[7]=(short)(pk >> 16);
            short8 bh = *(const short8*)&xh[lr][kt*32 + lg*8];
            acc = __builtin_amdgcn_mfma_f32_16x16x32_bf16(ah, bh, acc, 0, 0, 0);
            acc = __builtin_amdgcn_mfma_f32_16x16x32_bf16(al, bh, acc, 0, 0, 0);
            c0 = n0; c1 = n1;
        }

        // D: col = l&15 = token, row = (l>>4)*4 + reg.
        int tok = lr;
        if (tok < nn) {
            int p = lists[e*TOKENS + t0 + tok];
            #pragma unroll
            for (int u = 0; u < 2; ++u) {
                int rr = r0 + lg*4 + 2*u;             // even raw row
                float h0 = acc[2*u]   + b1[e*H2 + rr];
                float h1 = acc[2*u+1] + b1[e*H2 + rr + 1];
                float gv = fminf(h0, 7.f);
                float lvv = fminf(fmaxf(h1, -7.f), 7.f);
                float sg = 1.f / (1.f + __expf(-1.702f * gv));
                act[(size_t)p*HIDDEN + (rr >> 1)] = gv * sg * (lvv + 1.f);
            }
        }
    }
}

// ---------------- expert down-proj (MFMA, w2 split hi/lo, act bf16) -------
// block = 256 thr = 4 waves; wave owns 16 w2 rows x 16 tokens.
// grid (NEXP, DIM/64 = 8). Depth-2 prefetch.
__global__ __launch_bounds__(256, 4) void expert_down(
        const float* __restrict__ act, const float* __restrict__ w2,
        const float* __restrict__ b2, const int* __restrict__ counts,
        const int* __restrict__ lists, float* __restrict__ h2) {
    int e = blockIdx.x;
    int n = counts[e];
    if (n == 0) return;
    int tid = threadIdx.x;
    int wv = tid >> 6, l = tid & 63;
    int lr = l & 15, lg = l >> 4;
    __shared__ unsigned short as_[16][HIDDEN + PADK];  // 32.25 KB
    int r0 = blockIdx.y * 64 + wv * 16;    // output row tile base (0..511)
    const float4* w4 = (const float4*)(w2 + ((size_t)e*DIM + r0 + lr) * HIDDEN + lg * 8);

    for (int t0 = 0; t0 < n; t0 += 16) {
        int nn = min(16, n - t0);
        __syncthreads();
        for (int i = tid; i < 16 * (HIDDEN/4); i += 256) {
            int j = i >> 8, dd = i & 255;             // HIDDEN/4 = 256
            float4 v = make_float4(0.f, 0.f, 0.f, 0.f);
            if (j < nn) {
                int p = lists[e*TOKENS + t0 + j];
                v = *(const float4*)(act + (size_t)p*HIDDEN + 4*dd);
            }
            ushort4v hv;
            hv[0] = f2bf_rne(v.x); hv[1] = f2bf_rne(v.y);
            hv[2] = f2bf_rne(v.z); hv[3] = f2bf_rne(v.w);
            *(ushort4v*)&as_[j][4*dd] = hv;
        }
        __syncthreads();

        fp32x4 acc = {0.f, 0.f, 0.f, 0.f};
        float4 c0 = w4[0], c1 = w4[1];
        for (int kt = 0; kt < 32; ++kt) {
            float4 n0, n1;
            if (kt < 31) { n0 = w4[8*(kt+1)]; n1 = w4[8*(kt+1) + 1]; }
            short8 ah, al;
            unsigned pk;
            pk = split2p(c0.x); ah[0]=(short)(pk & 0xFFFF); al[0]=(short)(pk >> 16);
            pk = split2p(c0.y); ah[1]=(short)(pk & 0xFFFF); al[1]=(short)(pk >> 16);
            pk = split2p(c0.z); ah[2]=(short)(pk & 0xFFFF); al[2]=(short)(pk >> 16);
            pk = split2p(c0.w); ah[3]=(short)(pk & 0xFFFF); al[3]=(short)(pk >> 16);
            pk = split2p(c1.x); ah[4]=(short)(pk & 0xFFFF); al[4]=(short)(pk >> 16);
            pk = split2p(c1.y); ah[5]=(short)(pk & 0xFFFF); al[5]=(short)(pk >> 16);
            pk = split2p(c1.z); ah[6]=(short)(pk & 0xFFFF); al[6]=(short)(pk >> 16);
            pk = split2p(c1.w); ah[7]=(short)(pk & 0xFFFF); al[7]=(short)(pk >> 16);
            short8 bh = *(const short8*)&as_[lr][kt*32 + lg*8];
            acc = __builtin_amdgcn_mfma_f32_16x16x32_bf16(ah, bh, acc, 0, 0, 0);
            acc = __builtin_amdgcn_mfma_f32_16x16x32_bf16(al, bh, acc, 0, 0, 0);
            c0 = n0; c1 = n1;
        }

        int tok = lr;
        if (tok < nn) {
            int p = lists[e*TOKENS + t0 + tok];
            #pragma unroll
            for (int u = 0; u < 4; ++u) {
                int rr = r0 + lg*4 + u;
                h2[(size_t)p*DIM + rr] = acc[u] + b2[e*DIM + rr];
            }
        }
    }
}

// ---------------- weighted combine ----------------
__global__ void combine_kernel(const float* __restrict__ h2, const float* __restrict__ eww,
                               float* __restrict__ out) {
    int i = blockIdx.x * 256 + threadIdx.x;   // 0..32767
    int b = i / DIM;
    int c = i % DIM;
    float s = 0.f;
    #pragma unroll
    for (int k = 0; k < TOPK; ++k) {
        s += eww[b*TOPK + k] * h2[(size_t)(b*TOPK + k)*DIM + c];
    }
    out[i] = s;
}

extern "C" void kernel_launch(void* const* d_in, const int* in_sizes, int n_in,
                              void* d_out, int out_size, void* d_ws, size_t ws_size,
                              hipStream_t stream) {
    const float* x  = (const float*)d_in[0];
    const float* Wg = (const float*)d_in[1];
    const float* bg = (const float*)d_in[2];
    const float* w1 = (const float*)d_in[3];
    const float* b1 = (const float*)d_in[4];
    const float* w2 = (const float*)d_in[5];
    const float* b2 = (const float*)d_in[6];
    float* out = (float*)d_out;

    char* ws = (char*)d_ws;
    int*   idxw   = (int*)(ws);                 // 256 ints
    float* eww    = (float*)(ws + 1024);        // 256 floats
    int*   counts = (int*)(ws + 2048);          // 32 ints
    int*   lists  = (int*)(ws + 4096);          // 32*64 ints
    float* act    = (float*)(ws + 16384);                          // 256*1024 f32 = 1 MB
    float* h2     = (float*)(ws + 16384 + (size_t)NPAIR*HIDDEN*4); // 256*512 f32 = 512 KB

    router_kernel<<<TOKENS, 64, 0, stream>>>(x, Wg, bg, idxw, eww);
    build_lists<<<1, 256, 0, stream>>>(idxw, counts, lists);
    expert_up<<<dim3(NEXP, H2/64), 256, 0, stream>>>(x, w1, b1, counts, lists, act);
    expert_down<<<dim3(NEXP, DIM/64), 256, 0, stream>>>(act, w2, b2, counts, lists, h2);
    combine_kernel<<<TOKENS*DIM/256, 256, 0, stream>>>(h2, eww, out);
}

// Round 10
// 62.344 us; speedup vs baseline: 3.0076x; 1.3319x over previous
//
#include <hip/hip_runtime.h>

#define DIM 512
#define HIDDEN 1024
#define H2 2048        // 2*HIDDEN
#define NEXP 32
#define TOPK 4
#define TOKENS 64
#define NPAIR (TOKENS*TOPK)   // 256
#define PADK 8                // ushort pad per LDS row (2-way bank alias = free)

typedef __attribute__((ext_vector_type(8))) short short8;
typedef __attribute__((ext_vector_type(4))) float fp32x4;
typedef __attribute__((ext_vector_type(4))) unsigned short ushort4v;

// f32 -> bf16 round-nearest-even
__device__ __forceinline__ unsigned short f2bf_rne(float f) {
    unsigned u = __float_as_uint(f);
    return (unsigned short)((u + 0x7FFFu + ((u >> 16) & 1u)) >> 16);
}
// f32 -> packed (hi | lo<<16): hi = truncate-to-bf16, lo = RNE(residual)
__device__ __forceinline__ unsigned split2p(float f) {
    unsigned u = __float_as_uint(f);
    unsigned short h = (unsigned short)(u >> 16);
    float hf = __uint_as_float(u & 0xFFFF0000u);
    unsigned short lo = f2bf_rne(f - hf);
    return (unsigned)h | ((unsigned)lo << 16);
}
__device__ __forceinline__ float dot4f(float4 a, float4 b) {
    return a.x*b.x + a.y*b.y + a.z*b.z + a.w*b.w;
}

// ---------------- router: 16-way split-K logits + top4 + softmax ----------
// 64 blocks x 512 thr (lane = e*16 + s). Also zeroes out[b][:] for the
// fused atomic combine in expert_down.
__global__ __launch_bounds__(512) void router_kernel(
        const float* __restrict__ x, const float* __restrict__ Wg,
        const float* __restrict__ bg, int* __restrict__ idxw,
        float* __restrict__ eww, float* __restrict__ out) {
    int b = blockIdx.x;
    int tid = threadIdx.x;
    int e = tid >> 4, s = tid & 15;
    __shared__ float xs[DIM];
    __shared__ float g[NEXP];
    if (tid < DIM/4) {
        *(float4*)&xs[4*tid] = *(const float4*)(x + (size_t)b*DIM + 4*tid);
    }
    if (tid >= 128 && tid < 256) {
        int i = tid - 128;
        *(float4*)(out + (size_t)b*DIM + 4*i) = make_float4(0.f,0.f,0.f,0.f);
    }
    __syncthreads();
    const float* wr = Wg + e*DIM;
    float acc = 0.f;
    #pragma unroll
    for (int i = 0; i < 8; ++i) {         // 8 independent loads, batched
        int d4 = s + 16*i;
        float4 wv = *(const float4*)(wr + 4*d4);
        float4 xv = *(const float4*)&xs[4*d4];
        acc += dot4f(wv, xv);
    }
    #pragma unroll
    for (int m = 1; m < 16; m <<= 1) acc += __shfl_xor(acc, m);
    if (s == 0) g[e] = acc + bg[e];
    __syncthreads();
    if (tid == 0) {
        int sel[TOPK]; float val[TOPK];
        bool used[NEXP];
        for (int i = 0; i < NEXP; ++i) used[i] = false;
        for (int k = 0; k < TOPK; ++k) {
            float best = -1e30f; int bi = 0;
            for (int ee = 0; ee < NEXP; ++ee) {
                if (!used[ee] && g[ee] > best) { best = g[ee]; bi = ee; }
            }
            used[bi] = true; sel[k] = bi; val[k] = best;
        }
        float m = val[0];
        float p[TOPK]; float sum = 0.f;
        for (int k = 0; k < TOPK; ++k) { p[k] = __expf(val[k] - m); sum += p[k]; }
        float inv = 1.f / sum;
        for (int k = 0; k < TOPK; ++k) {
            idxw[b*TOPK + k] = sel[k];
            eww[b*TOPK + k]  = p[k] * inv;
        }
    }
}

// Inline deterministic per-expert list build (LDS). Caller: 256 threads.
// slist[r] = r-th pair (by pair index) assigned to expert e; returns count.
__device__ __forceinline__ int build_list_lds(
        const int* __restrict__ idxw, int e, int tid,
        int* sidx, int* slist, int* scnt) {
    if (tid == 0) *scnt = 0;
    sidx[tid] = idxw[tid];
    __syncthreads();
    int me = sidx[tid];
    if (me == e) {
        int r = 0;
        for (int q = 0; q < tid; ++q) r += (sidx[q] == e) ? 1 : 0;
        slist[r] = tid;
        atomicAdd(scnt, 1);       // LDS atomic, order-independent count
    }
    __syncthreads();
    return *scnt;
}

// ---------------- expert up-proj + swiglu (MFMA, w split hi/lo, x bf16) ---
// block = 256 thr = 4 waves; wave owns 16 raw w1 rows x 16 tokens.
// grid (NEXP, H2/64 = 32). 2 MFMAs per K-tile. Depth-2 prefetch.
__global__ __launch_bounds__(256, 4) void expert_up(
        const float* __restrict__ x, const float* __restrict__ w1,
        const float* __restrict__ b1, const int* __restrict__ idxw,
        float* __restrict__ act) {
    int e = blockIdx.x;
    int tid = threadIdx.x;
    __shared__ int sidx[NPAIR];
    __shared__ int slist[TOKENS];
    __shared__ int scnt;
    int n = build_list_lds(idxw, e, tid, sidx, slist, &scnt);
    if (n == 0) return;
    int wv = tid >> 6, l = tid & 63;
    int lr = l & 15, lg = l >> 4;          // A row-in-tile / k-group
    __shared__ unsigned short xh[16][DIM + PADK];   // 16.25 KB
    int r0 = blockIdx.y * 64 + wv * 16;    // raw row tile base (0..2047)
    const float4* w4 = (const float4*)(w1 + ((size_t)e*H2 + r0 + lr) * DIM + lg * 8);

    for (int t0 = 0; t0 < n; t0 += 16) {
        int nn = min(16, n - t0);
        __syncthreads();
        for (int i = tid; i < 16 * (DIM/4); i += 256) {
            int j = i >> 7, dd = i & 127;             // DIM/4 = 128
            float4 v = make_float4(0.f, 0.f, 0.f, 0.f);
            if (j < nn) {
                int p = slist[t0 + j];
                v = *(const float4*)(x + (size_t)(p >> 2)*DIM + 4*dd);
            }
            ushort4v hv;
            hv[0] = f2bf_rne(v.x); hv[1] = f2bf_rne(v.y);
            hv[2] = f2bf_rne(v.z); hv[3] = f2bf_rne(v.w);
            *(ushort4v*)&xh[j][4*dd] = hv;
        }
        __syncthreads();

        fp32x4 acc = {0.f, 0.f, 0.f, 0.f};
        float4 c0 = w4[0], c1 = w4[1];      // kt=0 in flight
        for (int kt = 0; kt < 16; ++kt) {
            float4 n0, n1;
            if (kt < 15) { n0 = w4[8*(kt+1)]; n1 = w4[8*(kt+1) + 1]; }
            short8 ah, al;
            unsigned pk;
            pk = split2p(c0.x); ah[0]=(short)(pk & 0xFFFF); al[0]=(short)(pk >> 16);
            pk = split2p(c0.y); ah[1]=(short)(pk & 0xFFFF); al[1]=(short)(pk >> 16);
            pk = split2p(c0.z); ah[2]=(short)(pk & 0xFFFF); al[2]=(short)(pk >> 16);
            pk = split2p(c0.w); ah[3]=(short)(pk & 0xFFFF); al[3]=(short)(pk >> 16);
            pk = split2p(c1.x); ah[4]=(short)(pk & 0xFFFF); al[4]=(short)(pk >> 16);
            pk = split2p(c1.y); ah[5]=(short)(pk & 0xFFFF); al[5]=(short)(pk >> 16);
            pk = split2p(c1.z); ah[6]=(short)(pk & 0xFFFF); al[6]=(short)(pk >> 16);
            pk = split2p(c1.w); ah[7]=(short)(pk & 0xFFFF); al[7]=(short)(pk >> 16);
            short8 bh = *(const short8*)&xh[lr][kt*32 + lg*8];
            acc = __builtin_amdgcn_mfma_f32_16x16x32_bf16(ah, bh, acc, 0, 0, 0);
            acc = __builtin_amdgcn_mfma_f32_16x16x32_bf16(al, bh, acc, 0, 0, 0);
            c0 = n0; c1 = n1;
        }

        // D: col = l&15 = token, row = (l>>4)*4 + reg.
        int tok = lr;
        if (tok < nn) {
            int p = slist[t0 + tok];
            #pragma unroll
            for (int u = 0; u < 2; ++u) {
                int rr = r0 + lg*4 + 2*u;             // even raw row
                float h0 = acc[2*u]   + b1[e*H2 + rr];
                float h1 = acc[2*u+1] + b1[e*H2 + rr + 1];
                float gv = fminf(h0, 7.f);
                float lvv = fminf(fmaxf(h1, -7.f), 7.f);
                float sg = 1.f / (1.f + __expf(-1.702f * gv));
                act[(size_t)p*HIDDEN + (rr >> 1)] = gv * sg * (lvv + 1.f);
            }
        }
    }
}

// ---------------- expert down-proj + fused weighted combine (atomicAdd) ---
// block = 256 thr = 4 waves; wave owns 16 w2 rows x 16 tokens.
// grid (NEXP, DIM/64 = 8). Depth-2 prefetch. out pre-zeroed by router.
__global__ __launch_bounds__(256, 4) void expert_down(
        const float* __restrict__ act, const float* __restrict__ w2,
        const float* __restrict__ b2, const int* __restrict__ idxw,
        const float* __restrict__ eww, float* __restrict__ out) {
    int e = blockIdx.x;
    int tid = threadIdx.x;
    __shared__ int sidx[NPAIR];
    __shared__ int slist[TOKENS];
    __shared__ int scnt;
    int n = build_list_lds(idxw, e, tid, sidx, slist, &scnt);
    if (n == 0) return;
    int wv = tid >> 6, l = tid & 63;
    int lr = l & 15, lg = l >> 4;
    __shared__ unsigned short as_[16][HIDDEN + PADK];  // 32.25 KB
    int r0 = blockIdx.y * 64 + wv * 16;    // output row tile base (0..511)
    const float4* w4 = (const float4*)(w2 + ((size_t)e*DIM + r0 + lr) * HIDDEN + lg * 8);

    for (int t0 = 0; t0 < n; t0 += 16) {
        int nn = min(16, n - t0);
        __syncthreads();
        for (int i = tid; i < 16 * (HIDDEN/4); i += 256) {
            int j = i >> 8, dd = i & 255;             // HIDDEN/4 = 256
            float4 v = make_float4(0.f, 0.f, 0.f, 0.f);
            if (j < nn) {
                int p = slist[t0 + j];
                v = *(const float4*)(act + (size_t)p*HIDDEN + 4*dd);
            }
            ushort4v hv;
            hv[0] = f2bf_rne(v.x); hv[1] = f2bf_rne(v.y);
            hv[2] = f2bf_rne(v.z); hv[3] = f2bf_rne(v.w);
            *(ushort4v*)&as_[j][4*dd] = hv;
        }
        __syncthreads();

        fp32x4 acc = {0.f, 0.f, 0.f, 0.f};
        float4 c0 = w4[0], c1 = w4[1];
        for (int kt = 0; kt < 32; ++kt) {
            float4 n0, n1;
            if (kt < 31) { n0 = w4[8*(kt+1)]; n1 = w4[8*(kt+1) + 1]; }
            short8 ah, al;
            unsigned pk;
            pk = split2p(c0.x); ah[0]=(short)(pk & 0xFFFF); al[0]=(short)(pk >> 16);
            pk = split2p(c0.y); ah[1]=(short)(pk & 0xFFFF); al[1]=(short)(pk >> 16);
            pk = split2p(c0.z); ah[2]=(short)(pk & 0xFFFF); al[2]=(short)(pk >> 16);
            pk = split2p(c0.w); ah[3]=(short)(pk & 0xFFFF); al[3]=(short)(pk >> 16);
            pk = split2p(c1.x); ah[4]=(short)(pk & 0xFFFF); al[4]=(short)(pk >> 16);
            pk = split2p(c1.y); ah[5]=(short)(pk & 0xFFFF); al[5]=(short)(pk >> 16);
            pk = split2p(c1.z); ah[6]=(short)(pk & 0xFFFF); al[6]=(short)(pk >> 16);
            pk = split2p(c1.w); ah[7]=(short)(pk & 0xFFFF); al[7]=(short)(pk >> 16);
            short8 bh = *(const short8*)&as_[lr][kt*32 + lg*8];
            acc = __builtin_amdgcn_mfma_f32_16x16x32_bf16(ah, bh, acc, 0, 0, 0);
            acc = __builtin_amdgcn_mfma_f32_16x16x32_bf16(al, bh, acc, 0, 0, 0);
            c0 = n0; c1 = n1;
        }

        int tok = lr;
        if (tok < nn) {
            int p = slist[t0 + tok];
            float ew = eww[p];
            int b = p >> 2;
            #pragma unroll
            for (int u = 0; u < 4; ++u) {
                int rr = r0 + lg*4 + u;
                atomicAdd(out + (size_t)b*DIM + rr, ew * (acc[u] + b2[e*DIM + rr]));
            }
        }
    }
}

extern "C" void kernel_launch(void* const* d_in, const int* in_sizes, int n_in,
                              void* d_out, int out_size, void* d_ws, size_t ws_size,
                              hipStream_t stream) {
    const float* x  = (const float*)d_in[0];
    const float* Wg = (const float*)d_in[1];
    const float* bg = (const float*)d_in[2];
    const float* w1 = (const float*)d_in[3];
    const float* b1 = (const float*)d_in[4];
    const float* w2 = (const float*)d_in[5];
    const float* b2 = (const float*)d_in[6];
    float* out = (float*)d_out;

    char* ws = (char*)d_ws;
    int*   idxw   = (int*)(ws);                 // 256 ints
    float* eww    = (float*)(ws + 1024);        // 256 floats
    float* act    = (float*)(ws + 16384);       // 256*1024 f32 = 1 MB

    router_kernel<<<TOKENS, 512, 0, stream>>>(x, Wg, bg, idxw, eww, out);
    expert_up<<<dim3(NEXP, H2/64), 256, 0, stream>>>(x, w1, b1, idxw, act);
    expert_down<<<dim3(NEXP, DIM/64), 256, 0, stream>>>(act, w2, b2, idxw, eww, out);
}